// Round 9
// baseline (222.002 us; speedup 1.0000x reference)
//
#include <hip/hip_runtime.h>
#include <stdint.h>
#include <stddef.h>

#define NB 2
#define NT 4096
#define NC 768
#define NH 12
#define ND 64

typedef unsigned short u16;
typedef __attribute__((ext_vector_type(2))) float f32x2;
typedef __attribute__((ext_vector_type(4))) float f32x4;
typedef __attribute__((ext_vector_type(16))) float f32x16;
typedef __attribute__((ext_vector_type(8))) unsigned short u16x8;
typedef __attribute__((ext_vector_type(4))) unsigned short u16x4;
typedef __attribute__((ext_vector_type(8))) __bf16 bf16x8;
typedef __attribute__((ext_vector_type(4))) unsigned int u32x4;

typedef __attribute__((address_space(1))) const unsigned int gu32;
typedef __attribute__((address_space(3))) unsigned int lu32;

__device__ __forceinline__ u16 f2bf(float f) {
  uint32_t u = __builtin_bit_cast(uint32_t, f);
  u += 0x7FFFu + ((u >> 16) & 1u);   // RTNE
  return (u16)(u >> 16);
}
__device__ __forceinline__ bf16x8 asbf(u16x8 v) { return __builtin_bit_cast(bf16x8, v); }

// pack two f32 -> two bf16, round-half-up: 3 VALU
__device__ __forceinline__ uint32_t pkbf(float a, float b) {
  uint32_t ua = __builtin_bit_cast(uint32_t, a) + 0x8000u;
  uint32_t ub = __builtin_bit_cast(uint32_t, b) + 0x8000u;
  return __builtin_amdgcn_perm(ub, ua, 0x07060302u);
}
// truncating pack (P only; numerator/denominator stay consistent): 1 VALU
__device__ __forceinline__ uint32_t pktr(float a, float b) {
  return __builtin_amdgcn_perm(__builtin_bit_cast(uint32_t, b),
                               __builtin_bit_cast(uint32_t, a), 0x07060302u);
}

#define GLDS(gsrc, ldst) __builtin_amdgcn_global_load_lds( \
    (gu32*)(gsrc), (lu32*)(ldst), 16, 0, 0)

// ------- merged preprocessing: cast(x) + transpose(w_qkv) + transpose(w_out)
#define PRE_CAST_BLKS 6144             // (NB*NT*NC/4)/256
#define PRE_TA_BX 72                   // 3*NC/32
#define PRE_TA_BLKS (72 * 24)
#define PRE_TB_BX 24                   // NC/32
#define PRE_TB_BLKS (24 * 24)
__global__ __launch_bounds__(256)
void k_pre(const float* __restrict__ x, u16* __restrict__ xb,
           const float* __restrict__ w_qkv, u16* __restrict__ wqT,
           const float* __restrict__ w_out, u16* __restrict__ woT) {
  __shared__ float tile[32][33];
  const int bid = blockIdx.x;
  const int tid = threadIdx.x;
  if (bid < PRE_CAST_BLKS) {
    int i = bid * 256 + tid;
    f32x4 v = ((const f32x4*)x)[i];
    u16x4 o;
    o[0] = f2bf(v[0]); o[1] = f2bf(v[1]); o[2] = f2bf(v[2]); o[3] = f2bf(v[3]);
    ((u16x4*)xb)[i] = o;
    return;
  }
  const float* in;
  u16* out;
  int R, Cn, bx, by;
  if (bid < PRE_CAST_BLKS + PRE_TA_BLKS) {
    int q = bid - PRE_CAST_BLKS;
    bx = q % PRE_TA_BX; by = q / PRE_TA_BX;
    in = w_qkv; out = wqT; R = NC; Cn = 3 * NC;
  } else {
    int q = bid - PRE_CAST_BLKS - PRE_TA_BLKS;
    bx = q % PRE_TB_BX; by = q / PRE_TB_BX;
    in = w_out; out = woT; R = NC; Cn = NC;
  }
  int c0 = bx * 32, r0 = by * 32;
  int tx = tid & 31, ty = tid >> 5;
  for (int i = ty; i < 32; i += 8)
    tile[i][tx] = in[(size_t)(r0 + i) * Cn + c0 + tx];
  __syncthreads();
  for (int i = ty; i < 32; i += 8)
    out[(size_t)(c0 + i) * R + r0 + tx] = f2bf(tile[tx][i]);
}

// -------- GEMM: C[M,N] = A[M,K] * Bt[N,K]^T  (m97 structure, BK=64) --------
// 1-D grid + XCD deswizzle (T1): nid = (wg&7)*cpx + wg>>3 -> each XCD owns 8
// contiguous m-panels x all n-tiles, so its A footprint (~1.5MB) and all of B
// fit its private L2; A/B panel re-reads move L3 -> L2.  NBX = n-tiles.
// Staging via global_load_lds dwordx4 into LINEAR LDS with T21 pre-swizzled
// SOURCE granule ((lane&7)^lr); ds_read at granule (want ^ (lc&7)) is
// conflict-free.  EPI==1 V-section transposes through SMEM and stores V^T as
// coalesced 256B segments (proven r7).
template <int EPI, int NBX>
__global__ __launch_bounds__(256, 3)
void k_gemm_bt(const u16* __restrict__ A, const u16* __restrict__ Bt,
               int M, int N, int K,
               u16* __restrict__ o0, u16* __restrict__ o1, u16* __restrict__ o2,
               float* __restrict__ of) {
  __shared__ u16 SMEM[2 * 128 * 64];   // As | Bs (16KB each); epi reuse
  u16* As = SMEM;
  u16* Bs = SMEM + 8192;
  const int tid = threadIdx.x;
  const int wave = tid >> 6, lane = tid & 63, quad = lane >> 4, lc = lane & 15;
  const int wm = (wave & 1) * 64, wn = (wave >> 1) * 64;
  const int wg = blockIdx.x;
  const int nid = (wg & 7) * ((int)gridDim.x >> 3) + (wg >> 3);
  const int bx = nid % NBX, by = nid / NBX;
  const int bm = by * 128, bn = bx * 128;

  // staging: wave w, chunk c covers rows c*32 + w*8 + lr (lr = lane>>3)
  const int lr = lane >> 3;
  const int gsw = ((lane & 7) ^ lr) * 8;          // pre-swizzled source granule
  const int rB = wave * 8 + lr;
  const u16* gA = A + (size_t)(bm + rB) * K + gsw;
  const u16* gB = Bt + (size_t)(bn + rB) * K + gsw;
  u16* lA0 = &As[wave * 8 * 64];                  // + c*2048 ; lane*16B linear
  u16* lB0 = &Bs[wave * 8 * 64];

  f32x4 zv = {0.f, 0.f, 0.f, 0.f};
  f32x4 acc[4][4];
#pragma unroll
  for (int i = 0; i < 4; ++i)
#pragma unroll
    for (int j = 0; j < 4; ++j) acc[i][j] = zv;

  for (int k0 = 0; k0 < K; k0 += 64) {
    __syncthreads();                 // prev iter's frag reads complete
#pragma unroll
    for (int c = 0; c < 4; ++c) {
      GLDS(gA + (size_t)c * 32 * K + k0, lA0 + c * 2048);
      GLDS(gB + (size_t)c * 32 * K + k0, lB0 + c * 2048);
    }
    asm volatile("s_waitcnt vmcnt(0)" ::: "memory");
    __syncthreads();                 // all waves' DMA landed

#pragma unroll
    for (int ks = 0; ks < 2; ++ks) {
      const int ao = (((ks << 2) + quad) ^ (lc & 7)) * 8;   // swizzled granule
      bf16x8 af[4], bfv[4];
#pragma unroll
      for (int mi = 0; mi < 4; ++mi)
        af[mi] = asbf(*(const u16x8*)&As[(wm + mi * 16 + lc) * 64 + ao]);
#pragma unroll
      for (int ni = 0; ni < 4; ++ni)
        bfv[ni] = asbf(*(const u16x8*)&Bs[(wn + ni * 16 + lc) * 64 + ao]);
#pragma unroll
      for (int mi = 0; mi < 4; ++mi)
#pragma unroll
        for (int ni = 0; ni < 4; ++ni)
          acc[mi][ni] = __builtin_amdgcn_mfma_f32_16x16x32_bf16(af[mi], bfv[ni],
                                                                acc[mi][ni], 0, 0, 0);
    }
  }

  const int sect = (EPI == 1) ? (bn / NC) : 0;   // block-uniform
  if (EPI == 1 && sect == 2) {
    // ---- V^T transposed epilogue through SMEM ----
    const int b = bm >> 12;
    const int tb = bm & (NT - 1);
    const int hb = (bn - 2 * NC) >> 6;
#pragma unroll 1
    for (int r2_ = 0; r2_ < 2; ++r2_) {
      __syncthreads();               // SMEM free / prev half read out
      if ((wave >> 1) == r2_) {      // waves owning wn == 64*r2_
#pragma unroll
        for (int mi = 0; mi < 4; ++mi)
#pragma unroll
          for (int ni = 0; ni < 4; ++ni) {
            const int nl = ni * 16 + lc;          // n within this 64-col half
#pragma unroll
            for (int r = 0; r < 4; ++r) {
              const int m = wm + mi * 16 + quad * 4 + r;
              SMEM[nl * 128 + (m ^ ((nl & 7) << 3))] = f2bf(acc[mi][ni][r]);
            }
          }
      }
      __syncthreads();
#pragma unroll
      for (int pass = 0; pass < 4; ++pass) {
        const int row = (tid >> 4) + 16 * pass;   // d-row within half
        const int chunk = tid & 15;               // 8-elem t-chunk
        u16x8 w = *(const u16x8*)&SMEM[row * 128 + ((chunk ^ (row & 7)) * 8)];
        const int nl = 64 * r2_ + row;
        *(u16x8*)&o2[((size_t)(b * NH + hb + (nl >> 6)) * ND + (nl & 63)) * NT
                     + tb + chunk * 8] = w;
      }
    }
    return;
  }

  const int mrow0 = bm + wm + quad * 4;
#pragma unroll
  for (int mi = 0; mi < 4; ++mi) {
    const int mbase = mrow0 + mi * 16;
#pragma unroll
    for (int ni = 0; ni < 4; ++ni) {
      const int n = bn + wn + ni * 16 + lc;
      if (EPI == 0) {
#pragma unroll
        for (int r = 0; r < 4; ++r)
          of[(size_t)(mbase + r) * N + n] = acc[mi][ni][r];
      } else {
        const int wn2 = n - sect * NC;
        const int h = wn2 >> 6, d = wn2 & 63;
        const int b = mbase >> 12;
        const int t = mbase & (NT - 1);
        const float sc = (sect == 0) ? 0.18033688011112042f : 1.0f;  // log2e/8
        u16* dst = (sect == 0) ? o0 : o1;
#pragma unroll
        for (int r = 0; r < 4; ++r)
          dst[((size_t)(b * NH + h) * NT + (t + r)) * ND + d] =
              f2bf(acc[mi][ni][r] * sc);
      }
    }
  }
}

// ============ flash attention: r2 structure + GLDS double-buffer (T3/T4) ====
// Grid = 24 bh x 64 q-tiles (descending qi).  Block = 4 waves (qh, th) as in
// r2.  THIS ROUND: staging is global_load_lds into a 2x16KB double buffer
// (linear dest + pre-swizzled SOURCE granule (lane&7)^lr, T21 — identical
// swizzle to the old soff, so qfro/vfro are unchanged), with counted
// s_waitcnt vmcnt(4) + raw s_barrier: next-tile DMAs stay in flight across
// both barriers, removing the global->reg->LDS serial section (r4-proven
// ordering: trailing barrier of iter tau-1 protects buf p^1 before its DMA).
// exp2 via raw v_exp_f32 (r8, -14 µs).  P in registers via pktr +
// permlane32_swap; denominator = truncated-exp sum + shfl_xor + LDS park.
__device__ __forceinline__ void softpack16(const f32x16& s, int qrel, bool msk,
                                           int l5, f32x2& sl2, bf16x8* pf) {
  float e[16];
#pragma unroll
  for (int r = 0; r < 16; ++r) {
    float v = s[r];
    if (msk) {
      int tl = (r & 3) + 8 * (r >> 2) + 4 * l5;   // 32x32 C-layout row
      v = (tl > qrel) ? -1e30f : v;
    }
    e[r] = __builtin_amdgcn_exp2f(v);
  }
  uint32_t wv[8];
#pragma unroll
  for (int i = 0; i < 8; ++i) {
    wv[i] = pktr(e[2 * i], e[2 * i + 1]);
    // denominator from the SAME truncated bf16 values the numerator uses
    f32x2 inc = {__builtin_bit_cast(float, wv[i] & 0xFFFF0000u),
                 __builtin_bit_cast(float, wv[i] << 16)};
    sl2 += inc;
  }
  // B-frag g covers t_local = g*16 + l5*8 + j; half-exchange = permlane32_swap
#pragma unroll
  for (int g = 0; g < 2; ++g) {
    auto r0 = __builtin_amdgcn_permlane32_swap(wv[g * 4 + 0], wv[g * 4 + 2], false, false);
    auto r1 = __builtin_amdgcn_permlane32_swap(wv[g * 4 + 1], wv[g * 4 + 3], false, false);
    u32x4 f = {r0[0], r1[0], r0[1], r1[1]};
    pf[g] = __builtin_bit_cast(bf16x8, f);
  }
}

__global__ __launch_bounds__(256, 3)
void k_attn(const u16* __restrict__ Q, const u16* __restrict__ K,
            const u16* __restrict__ Vt, u16* __restrict__ Y) {
  // dbuf: buf p at RAW[p*8192]: K tile [64t][64d] elems 0..4095, V^T tile
  // [64d][64t] elems 4096..8191.  Epilogue park overlays buf0 (64x64 f32).
  __shared__ u16 RAW[2 * 8192];
  __shared__ float PL[2][64];      // l park
  const int tid = threadIdx.x;
  const int lane = tid & 63, wave = tid >> 6;
  const int l5 = lane >> 5, l31 = lane & 31;
  const int qh = wave & 1, th = wave >> 1;
  const int bh = blockIdx.x % (NB * NH);
  const int qi = 63 - blockIdx.x / (NB * NH);      // long blocks first
  const int b = bh / NH, h = bh - b * NH;
  const u16* __restrict__ Qb = Q + (size_t)bh * NT * ND;
  const u16* __restrict__ Kb = K + (size_t)bh * NT * ND;
  const u16* __restrict__ Vb = Vt + (size_t)bh * (size_t)ND * NT;

  const int qg = qi * 64 + qh * 32 + l31;          // this lane's q column

  // Q as B-operand frags: col q = l31(+qh*32), k(d) = ks*16 + l5*8 + j
  bf16x8 bq[4];
#pragma unroll
  for (int ks = 0; ks < 4; ++ks)
    bq[ks] = asbf(*(const u16x8*)(Qb + (size_t)qg * ND + ks * 16 + l5 * 8));

  f32x16 Zv;
#pragma unroll
  for (int i = 0; i < 16; ++i) Zv[i] = 0.f;
  f32x16 o0 = Zv, o1 = Zv;     // O^T partial (d-halves), this wave's (qh,th)
  f32x2 sl2 = {0.f, 0.f};      // truncation-consistent partial l (2 lanes)

  // DMA staging: wave w stages rows [16w,16w+16) of K and of V via 4 GLDS.
  // LDS element layout: row*64 + (g ^ (row&7))*8 (row&7 == lr since r0w%8==0);
  // DMA writes linear lane*16B, so the SOURCE granule is pre-swizzled.
  const int lr = lane >> 3;
  const int gsw = ((lane & 7) ^ lr) * 8;           // inverse-swizzled granule
  const int r0w = wave * 16;
  const u16* gk0 = Kb + (size_t)(r0w + lr) * ND + gsw;       // + t0*ND
  const u16* gk1 = gk0 + (size_t)8 * ND;
  const u16* gv0 = Vb + (size_t)(r0w + lr) * NT + gsw;       // + t0
  const u16* gv1 = gv0 + (size_t)8 * NT;
  u16* lk = &RAW[r0w * 64];          // + p*8192 ; K region
  u16* lv = &RAW[4096 + r0w * 64];   // + p*8192 ; V region

  // LDS frag offsets (elements within a buffer), matching the XOR swizzle
  int qfro[4];
#pragma unroll
  for (int ks = 0; ks < 4; ++ks)
    qfro[ks] = (th * 32 + l31) * 64 + (((ks * 2 + l5) ^ (l31 & 7)) * 8);
  int vfro[2];
#pragma unroll
  for (int kp = 0; kp < 2; ++kp)
    vfro[kp] = 4096 + l31 * 64 + ((((2 * th + kp) * 2 + l5) ^ (l31 & 7)) * 8);

  // prologue: DMA tile 0 into buf 0
  GLDS(gk0, lk);
  GLDS(gk1, lk + 512);
  GLDS(gv0, lv);
  GLDS(gv1, lv + 512);

#pragma unroll 1
  for (int tau = 0; tau <= qi; ++tau) {
    const int p = tau & 1;
    if (tau < qi) {                  // issue next tile into other buf
      const int tn = (tau + 1) * 64;
      const int bo = (p ^ 1) * 8192;
      GLDS(gk0 + (size_t)tn * ND, lk + bo);
      GLDS(gk1 + (size_t)tn * ND, lk + bo + 512);
      GLDS(gv0 + tn, lv + bo);
      GLDS(gv1 + tn, lv + bo + 512);
      asm volatile("s_waitcnt vmcnt(4)" ::: "memory");  // tile tau landed
    } else {
      asm volatile("s_waitcnt vmcnt(0)" ::: "memory");
    }
    __builtin_amdgcn_s_barrier();    // all waves' tile-tau DMA complete

    const bool dg = (tau == qi);
    const bool act = !(dg && th > qh);    // wave-uniform
    if (act) {
      const u16* bufp = &RAW[p * 8192];
      // S^T[32t x 32q] = K(th half) Q(qh)^T ; first MFMA consumes Zv as C
      bf16x8 kf0 = asbf(*(const u16x8*)&bufp[qfro[0]]);
      __builtin_amdgcn_s_setprio(1);
      f32x16 s = __builtin_amdgcn_mfma_f32_32x32x16_bf16(kf0, bq[0], Zv, 0, 0, 0);
#pragma unroll
      for (int ks = 1; ks < 4; ++ks) {
        bf16x8 kf = asbf(*(const u16x8*)&bufp[qfro[ks]]);
        s = __builtin_amdgcn_mfma_f32_32x32x16_bf16(kf, bq[ks], s, 0, 0, 0);
      }
      __builtin_amdgcn_s_setprio(0);
      bf16x8 p2[2];
      softpack16(s, l31, dg && (th == qh), l5, sl2, p2);

      // O^T += V^T(d-halves) P^T(this wave's t-slice)
      __builtin_amdgcn_s_setprio(1);
#pragma unroll
      for (int kp = 0; kp < 2; ++kp) {
        bf16x8 v0 = asbf(*(const u16x8*)&bufp[vfro[kp]]);
        bf16x8 v1 = asbf(*(const u16x8*)&bufp[vfro[kp] + 2048]);
        o0 = __builtin_amdgcn_mfma_f32_32x32x16_bf16(v0, p2[kp], o0, 0, 0, 0);
        o1 = __builtin_amdgcn_mfma_f32_32x32x16_bf16(v1, p2[kp], o1, 0, 0, 0);
      }
      __builtin_amdgcn_s_setprio(0);
    }
    __builtin_amdgcn_s_barrier();    // all waves done reading buf p
  }

  // ---- epilogue: combine l5 halves, then th-pair waves via LDS park ----
  const float slv = sl2[0] + sl2[1];
  float l = slv + __shfl_xor(slv, 32);
  __syncthreads();                       // done reading RAW as K/V
  float* PK = (float*)&RAW[0];           // 16KB park: [64 rows][64 lanes] f32
  if (th == 0) {
#pragma unroll
    for (int r = 0; r < 16; ++r) PK[(qh * 32 + r) * 64 + lane] = o0[r];
#pragma unroll
    for (int r = 0; r < 16; ++r) PK[(qh * 32 + 16 + r) * 64 + lane] = o1[r];
    PL[qh][lane] = l;
  }
  __syncthreads();
  if (th == 1) {
#pragma unroll
    for (int r = 0; r < 16; ++r) o0[r] += PK[(qh * 32 + r) * 64 + lane];
#pragma unroll
    for (int r = 0; r < 16; ++r) o1[r] += PK[(qh * 32 + 16 + r) * 64 + lane];
    l += PL[qh][lane];
    const float inv = 1.f / l;
    u16* yrow = Y + (size_t)(b * NT + qg) * NC + h * 64;
#pragma unroll
    for (int dh = 0; dh < 2; ++dh) {
      const f32x16& o = dh ? o1 : o0;
#pragma unroll
      for (int rq = 0; rq < 4; ++rq) {
        const int d = dh * 32 + 8 * rq + 4 * l5;
        uint2 w;
        w.x = pkbf(o[rq * 4 + 0] * inv, o[rq * 4 + 1] * inv);
        w.y = pkbf(o[rq * 4 + 2] * inv, o[rq * 4 + 3] * inv);
        *(uint2*)&yrow[d] = w;
      }
    }
  }
}

extern "C" void kernel_launch(void* const* d_in, const int* in_sizes, int n_in,
                              void* d_out, int out_size, void* d_ws, size_t ws_size,
                              hipStream_t stream) {
  (void)in_sizes; (void)n_in; (void)out_size; (void)ws_size;
  const float* x = (const float*)d_in[0];
  const float* w_qkv = (const float*)d_in[1];
  const float* w_out = (const float*)d_in[2];
  float* out = (float*)d_out;

  u16* ws = (u16*)d_ws;
  const size_t XE = (size_t)NB * NT * NC;       // 6291456 elements
  u16* xb  = ws;
  u16* wqT = xb + XE;
  u16* woT = wqT + (size_t)3 * NC * NC;
  u16* Qb  = woT + (size_t)NC * NC;
  u16* Kb  = Qb + XE;
  u16* Vtb = Kb + XE;
  u16* yb  = Vtb + XE;

  k_pre<<<dim3(PRE_CAST_BLKS + PRE_TA_BLKS + PRE_TB_BLKS), 256, 0, stream>>>(
      x, xb, w_qkv, wqT, w_out, woT);
  k_gemm_bt<1, 18><<<dim3(18 * 64), 256, 0, stream>>>(
      xb, wqT, NB * NT, 3 * NC, NC, Qb, Kb, Vtb, nullptr);
  k_attn<<<dim3((NB * NH) * 64), 256, 0, stream>>>(Qb, Kb, Vtb, yb);
  k_gemm_bt<0, 6><<<dim3(6 * 64), 256, 0, stream>>>(
      yb, woT, NB * NT, NC, NC, nullptr, nullptr, nullptr, out);
}

// Round 10
// 218.610 us; speedup vs baseline: 1.0155x; 1.0155x over previous
//
#include <hip/hip_runtime.h>
#include <stdint.h>
#include <stddef.h>

#define NB 2
#define NT 4096
#define NC 768
#define NH 12
#define ND 64

typedef unsigned short u16;
typedef __attribute__((ext_vector_type(2))) float f32x2;
typedef __attribute__((ext_vector_type(4))) float f32x4;
typedef __attribute__((ext_vector_type(16))) float f32x16;
typedef __attribute__((ext_vector_type(8))) unsigned short u16x8;
typedef __attribute__((ext_vector_type(4))) unsigned short u16x4;
typedef __attribute__((ext_vector_type(8))) __bf16 bf16x8;
typedef __attribute__((ext_vector_type(4))) unsigned int u32x4;

typedef __attribute__((address_space(1))) const unsigned int gu32;
typedef __attribute__((address_space(3))) unsigned int lu32;

__device__ __forceinline__ u16 f2bf(float f) {
  uint32_t u = __builtin_bit_cast(uint32_t, f);
  u += 0x7FFFu + ((u >> 16) & 1u);   // RTNE
  return (u16)(u >> 16);
}
__device__ __forceinline__ bf16x8 asbf(u16x8 v) { return __builtin_bit_cast(bf16x8, v); }

// pack two f32 -> two bf16, round-half-up: 3 VALU
__device__ __forceinline__ uint32_t pkbf(float a, float b) {
  uint32_t ua = __builtin_bit_cast(uint32_t, a) + 0x8000u;
  uint32_t ub = __builtin_bit_cast(uint32_t, b) + 0x8000u;
  return __builtin_amdgcn_perm(ub, ua, 0x07060302u);
}
// truncating pack (P only; numerator/denominator stay consistent): 1 VALU
__device__ __forceinline__ uint32_t pktr(float a, float b) {
  return __builtin_amdgcn_perm(__builtin_bit_cast(uint32_t, b),
                               __builtin_bit_cast(uint32_t, a), 0x07060302u);
}

#define GLDS(gsrc, ldst) __builtin_amdgcn_global_load_lds( \
    (gu32*)(gsrc), (lu32*)(ldst), 16, 0, 0)

// ------- merged preprocessing: cast(x) + transpose(w_qkv) + transpose(w_out)
#define PRE_CAST_BLKS 6144             // (NB*NT*NC/4)/256
#define PRE_TA_BX 72                   // 3*NC/32
#define PRE_TA_BLKS (72 * 24)
#define PRE_TB_BX 24                   // NC/32
#define PRE_TB_BLKS (24 * 24)
__global__ __launch_bounds__(256)
void k_pre(const float* __restrict__ x, u16* __restrict__ xb,
           const float* __restrict__ w_qkv, u16* __restrict__ wqT,
           const float* __restrict__ w_out, u16* __restrict__ woT) {
  __shared__ float tile[32][33];
  const int bid = blockIdx.x;
  const int tid = threadIdx.x;
  if (bid < PRE_CAST_BLKS) {
    int i = bid * 256 + tid;
    f32x4 v = ((const f32x4*)x)[i];
    u16x4 o;
    o[0] = f2bf(v[0]); o[1] = f2bf(v[1]); o[2] = f2bf(v[2]); o[3] = f2bf(v[3]);
    ((u16x4*)xb)[i] = o;
    return;
  }
  const float* in;
  u16* out;
  int R, Cn, bx, by;
  if (bid < PRE_CAST_BLKS + PRE_TA_BLKS) {
    int q = bid - PRE_CAST_BLKS;
    bx = q % PRE_TA_BX; by = q / PRE_TA_BX;
    in = w_qkv; out = wqT; R = NC; Cn = 3 * NC;
  } else {
    int q = bid - PRE_CAST_BLKS - PRE_TA_BLKS;
    bx = q % PRE_TB_BX; by = q / PRE_TB_BX;
    in = w_out; out = woT; R = NC; Cn = NC;
  }
  int c0 = bx * 32, r0 = by * 32;
  int tx = tid & 31, ty = tid >> 5;
  for (int i = ty; i < 32; i += 8)
    tile[i][tx] = in[(size_t)(r0 + i) * Cn + c0 + tx];
  __syncthreads();
  for (int i = ty; i < 32; i += 8)
    out[(size_t)(c0 + i) * R + r0 + tx] = f2bf(tile[tx][i]);
}

// -------- GEMM: C[M,N] = A[M,K] * Bt[N,K]^T  (m97 structure, BK=64) --------
// 1-D grid + XCD deswizzle (T1, r9: ~-4 µs): nid = (wg&7)*cpx + wg>>3 ->
// each XCD owns contiguous m-panels x all n-tiles; A/B panel re-reads move
// L3 -> its private L2.  Staging via global_load_lds dwordx4 into LINEAR LDS
// with T21 pre-swizzled SOURCE granule ((lane&7)^lr); ds_read at granule
// (want ^ (lc&7)) is conflict-free.  EPI==1 V-section transposes through
// SMEM and stores V^T as coalesced 256B segments (proven r7).
template <int EPI, int NBX>
__global__ __launch_bounds__(256, 3)
void k_gemm_bt(const u16* __restrict__ A, const u16* __restrict__ Bt,
               int M, int N, int K,
               u16* __restrict__ o0, u16* __restrict__ o1, u16* __restrict__ o2,
               float* __restrict__ of) {
  __shared__ u16 SMEM[2 * 128 * 64];   // As | Bs (16KB each); epi reuse
  u16* As = SMEM;
  u16* Bs = SMEM + 8192;
  const int tid = threadIdx.x;
  const int wave = tid >> 6, lane = tid & 63, quad = lane >> 4, lc = lane & 15;
  const int wm = (wave & 1) * 64, wn = (wave >> 1) * 64;
  const int wg = blockIdx.x;
  const int nid = (wg & 7) * ((int)gridDim.x >> 3) + (wg >> 3);
  const int bx = nid % NBX, by = nid / NBX;
  const int bm = by * 128, bn = bx * 128;

  // staging: wave w, chunk c covers rows c*32 + w*8 + lr (lr = lane>>3)
  const int lr = lane >> 3;
  const int gsw = ((lane & 7) ^ lr) * 8;          // pre-swizzled source granule
  const int rB = wave * 8 + lr;
  const u16* gA = A + (size_t)(bm + rB) * K + gsw;
  const u16* gB = Bt + (size_t)(bn + rB) * K + gsw;
  u16* lA0 = &As[wave * 8 * 64];                  // + c*2048 ; lane*16B linear
  u16* lB0 = &Bs[wave * 8 * 64];

  f32x4 zv = {0.f, 0.f, 0.f, 0.f};
  f32x4 acc[4][4];
#pragma unroll
  for (int i = 0; i < 4; ++i)
#pragma unroll
    for (int j = 0; j < 4; ++j) acc[i][j] = zv;

  for (int k0 = 0; k0 < K; k0 += 64) {
    __syncthreads();                 // prev iter's frag reads complete
#pragma unroll
    for (int c = 0; c < 4; ++c) {
      GLDS(gA + (size_t)c * 32 * K + k0, lA0 + c * 2048);
      GLDS(gB + (size_t)c * 32 * K + k0, lB0 + c * 2048);
    }
    asm volatile("s_waitcnt vmcnt(0)" ::: "memory");
    __syncthreads();                 // all waves' DMA landed

#pragma unroll
    for (int ks = 0; ks < 2; ++ks) {
      const int ao = (((ks << 2) + quad) ^ (lc & 7)) * 8;   // swizzled granule
      bf16x8 af[4], bfv[4];
#pragma unroll
      for (int mi = 0; mi < 4; ++mi)
        af[mi] = asbf(*(const u16x8*)&As[(wm + mi * 16 + lc) * 64 + ao]);
#pragma unroll
      for (int ni = 0; ni < 4; ++ni)
        bfv[ni] = asbf(*(const u16x8*)&Bs[(wn + ni * 16 + lc) * 64 + ao]);
#pragma unroll
      for (int mi = 0; mi < 4; ++mi)
#pragma unroll
        for (int ni = 0; ni < 4; ++ni)
          acc[mi][ni] = __builtin_amdgcn_mfma_f32_16x16x32_bf16(af[mi], bfv[ni],
                                                                acc[mi][ni], 0, 0, 0);
    }
  }

  const int sect = (EPI == 1) ? (bn / NC) : 0;   // block-uniform
  if (EPI == 1 && sect == 2) {
    // ---- V^T transposed epilogue through SMEM ----
    const int b = bm >> 12;
    const int tb = bm & (NT - 1);
    const int hb = (bn - 2 * NC) >> 6;
#pragma unroll 1
    for (int r2_ = 0; r2_ < 2; ++r2_) {
      __syncthreads();               // SMEM free / prev half read out
      if ((wave >> 1) == r2_) {      // waves owning wn == 64*r2_
#pragma unroll
        for (int mi = 0; mi < 4; ++mi)
#pragma unroll
          for (int ni = 0; ni < 4; ++ni) {
            const int nl = ni * 16 + lc;          // n within this 64-col half
#pragma unroll
            for (int r = 0; r < 4; ++r) {
              const int m = wm + mi * 16 + quad * 4 + r;
              SMEM[nl * 128 + (m ^ ((nl & 7) << 3))] = f2bf(acc[mi][ni][r]);
            }
          }
      }
      __syncthreads();
#pragma unroll
      for (int pass = 0; pass < 4; ++pass) {
        const int row = (tid >> 4) + 16 * pass;   // d-row within half
        const int chunk = tid & 15;               // 8-elem t-chunk
        u16x8 w = *(const u16x8*)&SMEM[row * 128 + ((chunk ^ (row & 7)) * 8)];
        const int nl = 64 * r2_ + row;
        *(u16x8*)&o2[((size_t)(b * NH + hb + (nl >> 6)) * ND + (nl & 63)) * NT
                     + tb + chunk * 8] = w;
      }
    }
    return;
  }

  const int mrow0 = bm + wm + quad * 4;
#pragma unroll
  for (int mi = 0; mi < 4; ++mi) {
    const int mbase = mrow0 + mi * 16;
#pragma unroll
    for (int ni = 0; ni < 4; ++ni) {
      const int n = bn + wn + ni * 16 + lc;
      if (EPI == 0) {
#pragma unroll
        for (int r = 0; r < 4; ++r)
          of[(size_t)(mbase + r) * N + n] = acc[mi][ni][r];
      } else {
        const int wn2 = n - sect * NC;
        const int h = wn2 >> 6, d = wn2 & 63;
        const int b = mbase >> 12;
        const int t = mbase & (NT - 1);
        const float sc = (sect == 0) ? 0.18033688011112042f : 1.0f;  // log2e/8
        u16* dst = (sect == 0) ? o0 : o1;
#pragma unroll
        for (int r = 0; r < 4; ++r)
          dst[((size_t)(b * NH + h) * NT + (t + r)) * ND + d] =
              f2bf(acc[mi][ni][r] * sc);
      }
    }
  }
}

// ============ flash attention (r8 structure, verbatim) + 4 blocks/CU ========
// Grid = 24 bh x 64 q-tiles (descending qi).  Block = 4 waves (qh, th); reg-
// staged K/V tile (16KB, XOR swizzle g^(row&7)); P in registers via pktr +
// permlane32_swap; raw v_exp_f32 (r8, -14 µs); truncated-exp denominator.
// THIS ROUND: __launch_bounds__(256, 4) — r8's (256,3) let regalloc grow to
// the ~170 cap (VGPR_Count 56 shown excludes AGPR), capping residency at 3
// blocks/CU with every pipe <50% busy.  Live-state audit (~105-115 regs)
// fits the 128 cap -> 4 blocks/CU -> 4/3 more cross-block overlap.
__device__ __forceinline__ void softpack16(const f32x16& s, int qrel, bool msk,
                                           int l5, f32x2& sl2, bf16x8* pf) {
  float e[16];
#pragma unroll
  for (int r = 0; r < 16; ++r) {
    float v = s[r];
    if (msk) {
      int tl = (r & 3) + 8 * (r >> 2) + 4 * l5;   // 32x32 C-layout row
      v = (tl > qrel) ? -1e30f : v;
    }
    e[r] = __builtin_amdgcn_exp2f(v);
  }
  uint32_t wv[8];
#pragma unroll
  for (int i = 0; i < 8; ++i) {
    wv[i] = pktr(e[2 * i], e[2 * i + 1]);
    // denominator from the SAME truncated bf16 values the numerator uses
    f32x2 inc = {__builtin_bit_cast(float, wv[i] & 0xFFFF0000u),
                 __builtin_bit_cast(float, wv[i] << 16)};
    sl2 += inc;
  }
  // B-frag g covers t_local = g*16 + l5*8 + j; half-exchange = permlane32_swap
#pragma unroll
  for (int g = 0; g < 2; ++g) {
    auto r0 = __builtin_amdgcn_permlane32_swap(wv[g * 4 + 0], wv[g * 4 + 2], false, false);
    auto r1 = __builtin_amdgcn_permlane32_swap(wv[g * 4 + 1], wv[g * 4 + 3], false, false);
    u32x4 f = {r0[0], r1[0], r0[1], r1[1]};
    pf[g] = __builtin_bit_cast(bf16x8, f);
  }
}

__global__ __launch_bounds__(256, 4)
void k_attn(const u16* __restrict__ Q, const u16* __restrict__ K,
            const u16* __restrict__ Vt, u16* __restrict__ Y) {
  __shared__ u16 SM[2][64 * 64];   // [0]=K tile [t][d], [1]=V^T tile [d][t]
  __shared__ float PL[2][64];      // l park
  const int tid = threadIdx.x;
  const int lane = tid & 63, wave = tid >> 6;
  const int l5 = lane >> 5, l31 = lane & 31;
  const int qh = wave & 1, th = wave >> 1;
  const int bh = blockIdx.x % (NB * NH);
  const int qi = 63 - blockIdx.x / (NB * NH);      // long blocks first
  const int b = bh / NH, h = bh - b * NH;
  const u16* __restrict__ Qb = Q + (size_t)bh * NT * ND;
  const u16* __restrict__ Kb = K + (size_t)bh * NT * ND;
  const u16* __restrict__ Vb = Vt + (size_t)bh * (size_t)ND * NT;

  const int qg = qi * 64 + qh * 32 + l31;          // this lane's q column

  // Q as B-operand frags: col q = l31(+qh*32), k(d) = ks*16 + l5*8 + j
  bf16x8 bq[4];
#pragma unroll
  for (int ks = 0; ks < 4; ++ks)
    bq[ks] = asbf(*(const u16x8*)(Qb + (size_t)qg * ND + ks * 16 + l5 * 8));

  f32x16 Zv;
#pragma unroll
  for (int i = 0; i < 16; ++i) Zv[i] = 0.f;
  f32x16 o0 = Zv, o1 = Zv;     // O^T partial (d-halves), this wave's (qh,th)
  f32x2 sl2 = {0.f, 0.f};      // truncation-consistent partial l (2 lanes)

  // staging: 256 thr x 4 x 16B = 16KB/iter; dest XOR-swizzled
  const int srow = tid >> 3, sg = tid & 7;
  const int soff = srow * 64 + ((sg ^ (srow & 7)) * 8);
  const u16* __restrict__ pK = Kb + (size_t)srow * ND + sg * 8;
  const u16* __restrict__ pV = Vb + (size_t)srow * NT + sg * 8;

  // LDS frag offsets (elements), matching XOR swizzle
  int qfro[4];
#pragma unroll
  for (int ks = 0; ks < 4; ++ks)
    qfro[ks] = (th * 32 + l31) * 64 + (((ks * 2 + l5) ^ (l31 & 7)) * 8);
  int vfro[2];
#pragma unroll
  for (int kp = 0; kp < 2; ++kp)
    vfro[kp] = l31 * 64 + ((((2 * th + kp) * 2 + l5) ^ (l31 & 7)) * 8);

  // prefetch tile 0
  u16x8 st[4];
  st[0] = *(const u16x8*)(pK);
  st[1] = *(const u16x8*)(pK + (size_t)32 * ND);
  st[2] = *(const u16x8*)(pV);
  st[3] = *(const u16x8*)(pV + (size_t)32 * NT);

#pragma unroll 1
  for (int tau = 0; tau <= qi; ++tau) {
    __syncthreads();
    *(u16x8*)&SM[0][soff] = st[0];
    *(u16x8*)&SM[0][2048 + soff] = st[1];
    *(u16x8*)&SM[1][soff] = st[2];
    *(u16x8*)&SM[1][2048 + soff] = st[3];
    __syncthreads();

    const bool dg = (tau == qi);
    const bool act = !(dg && th > qh);    // wave-uniform
    bf16x8 p[2];
    if (act) {
      // S^T[32t x 32q] = K(th half) Q(qh)^T ; first MFMA consumes Zv as C
      bf16x8 kf0 = asbf(*(const u16x8*)&SM[0][qfro[0]]);
      __builtin_amdgcn_s_setprio(1);
      f32x16 s = __builtin_amdgcn_mfma_f32_32x32x16_bf16(kf0, bq[0], Zv, 0, 0, 0);
#pragma unroll
      for (int ks = 1; ks < 4; ++ks) {
        bf16x8 kf = asbf(*(const u16x8*)&SM[0][qfro[ks]]);
        s = __builtin_amdgcn_mfma_f32_32x32x16_bf16(kf, bq[ks], s, 0, 0, 0);
      }
      __builtin_amdgcn_s_setprio(0);
      softpack16(s, l31, dg && (th == qh), l5, sl2, p);
    }

    // prefetch next tile (all threads; hides HBM latency under PV)
    if (tau < qi) {
      const int tn = (tau + 1) * 64;
      st[0] = *(const u16x8*)(pK + (size_t)tn * ND);
      st[1] = *(const u16x8*)(pK + (size_t)(tn + 32) * ND);
      st[2] = *(const u16x8*)(pV + tn);
      st[3] = *(const u16x8*)(pV + (size_t)32 * NT + tn);
    }

    if (act) {
      // O^T += V^T(d-halves) P^T(this wave's t-slice)
      __builtin_amdgcn_s_setprio(1);
#pragma unroll
      for (int kp = 0; kp < 2; ++kp) {
        bf16x8 v0 = asbf(*(const u16x8*)&SM[1][vfro[kp]]);
        bf16x8 v1 = asbf(*(const u16x8*)&SM[1][2048 + vfro[kp]]);
        o0 = __builtin_amdgcn_mfma_f32_32x32x16_bf16(v0, p[kp], o0, 0, 0, 0);
        o1 = __builtin_amdgcn_mfma_f32_32x32x16_bf16(v1, p[kp], o1, 0, 0, 0);
      }
      __builtin_amdgcn_s_setprio(0);
    }
  }

  // ---- epilogue: combine l5 halves, then th-pair waves via LDS park ----
  const float slv = sl2[0] + sl2[1];
  float l = slv + __shfl_xor(slv, 32);
  __syncthreads();                       // done reading SM as K/V
  float* PK = (float*)&SM[0][0];         // 16KB park: [64 rows][64 lanes] f32
  if (th == 0) {
#pragma unroll
    for (int r = 0; r < 16; ++r) PK[(qh * 32 + r) * 64 + lane] = o0[r];
#pragma unroll
    for (int r = 0; r < 16; ++r) PK[(qh * 32 + 16 + r) * 64 + lane] = o1[r];
    PL[qh][lane] = l;
  }
  __syncthreads();
  if (th == 1) {
#pragma unroll
    for (int r = 0; r < 16; ++r) o0[r] += PK[(qh * 32 + r) * 64 + lane];
#pragma unroll
    for (int r = 0; r < 16; ++r) o1[r] += PK[(qh * 32 + 16 + r) * 64 + lane];
    l += PL[qh][lane];
    const float inv = 1.f / l;
    u16* yrow = Y + (size_t)(b * NT + qg) * NC + h * 64;
#pragma unroll
    for (int dh = 0; dh < 2; ++dh) {
      const f32x16& o = dh ? o1 : o0;
#pragma unroll
      for (int rq = 0; rq < 4; ++rq) {
        const int d = dh * 32 + 8 * rq + 4 * l5;
        uint2 w;
        w.x = pkbf(o[rq * 4 + 0] * inv, o[rq * 4 + 1] * inv);
        w.y = pkbf(o[rq * 4 + 2] * inv, o[rq * 4 + 3] * inv);
        *(uint2*)&yrow[d] = w;
      }
    }
  }
}

extern "C" void kernel_launch(void* const* d_in, const int* in_sizes, int n_in,
                              void* d_out, int out_size, void* d_ws, size_t ws_size,
                              hipStream_t stream) {
  (void)in_sizes; (void)n_in; (void)out_size; (void)ws_size;
  const float* x = (const float*)d_in[0];
  const float* w_qkv = (const float*)d_in[1];
  const float* w_out = (const float*)d_in[2];
  float* out = (float*)d_out;

  u16* ws = (u16*)d_ws;
  const size_t XE = (size_t)NB * NT * NC;       // 6291456 elements
  u16* xb  = ws;
  u16* wqT = xb + XE;
  u16* woT = wqT + (size_t)3 * NC * NC;
  u16* Qb  = woT + (size_t)NC * NC;
  u16* Kb  = Qb + XE;
  u16* Vtb = Kb + XE;
  u16* yb  = Vtb + XE;

  k_pre<<<dim3(PRE_CAST_BLKS + PRE_TA_BLKS + PRE_TB_BLKS), 256, 0, stream>>>(
      x, xb, w_qkv, wqT, w_out, woT);
  k_gemm_bt<1, 18><<<dim3(18 * 64), 256, 0, stream>>>(
      xb, wqT, NB * NT, 3 * NC, NC, Qb, Kb, Vtb, nullptr);
  k_attn<<<dim3((NB * NH) * 64), 256, 0, stream>>>(Qb, Kb, Vtb, yb);
  k_gemm_bt<0, 6><<<dim3(6 * 64), 256, 0, stream>>>(
      yb, woT, NB * NT, NC, NC, nullptr, nullptr, nullptr, out);
}

// Round 11
// 214.425 us; speedup vs baseline: 1.0353x; 1.0195x over previous
//
#include <hip/hip_runtime.h>
#include <stdint.h>
#include <stddef.h>

#define NB 2
#define NT 4096
#define NC 768
#define NH 12
#define ND 64

typedef unsigned short u16;
typedef __attribute__((ext_vector_type(4))) float f32x4;
typedef __attribute__((ext_vector_type(16))) float f32x16;
typedef __attribute__((ext_vector_type(8))) unsigned short u16x8;
typedef __attribute__((ext_vector_type(4))) unsigned short u16x4;
typedef __attribute__((ext_vector_type(8))) __bf16 bf16x8;
typedef __attribute__((ext_vector_type(4))) unsigned int u32x4;

typedef __attribute__((address_space(1))) const unsigned int gu32;
typedef __attribute__((address_space(3))) unsigned int lu32;

__device__ __forceinline__ u16 f2bf(float f) {
  uint32_t u = __builtin_bit_cast(uint32_t, f);
  u += 0x7FFFu + ((u >> 16) & 1u);   // RTNE
  return (u16)(u >> 16);
}
__device__ __forceinline__ bf16x8 asbf(u16x8 v) { return __builtin_bit_cast(bf16x8, v); }

// pack two f32 -> two bf16, round-half-up: 3 VALU
__device__ __forceinline__ uint32_t pkbf(float a, float b) {
  uint32_t ua = __builtin_bit_cast(uint32_t, a) + 0x8000u;
  uint32_t ub = __builtin_bit_cast(uint32_t, b) + 0x8000u;
  return __builtin_amdgcn_perm(ub, ua, 0x07060302u);
}
// truncating pack (P only; numerator/denominator stay consistent): 1 VALU
__device__ __forceinline__ uint32_t pktr(float a, float b) {
  return __builtin_amdgcn_perm(__builtin_bit_cast(uint32_t, b),
                               __builtin_bit_cast(uint32_t, a), 0x07060302u);
}

#define GLDS(gsrc, ldst) __builtin_amdgcn_global_load_lds( \
    (gu32*)(gsrc), (lu32*)(ldst), 16, 0, 0)

// ------- merged preprocessing: cast(x) + transpose(w_qkv) + transpose(w_out)
#define PRE_CAST_BLKS 6144             // (NB*NT*NC/4)/256
#define PRE_TA_BX 72                   // 3*NC/32
#define PRE_TA_BLKS (72 * 24)
#define PRE_TB_BX 24                   // NC/32
#define PRE_TB_BLKS (24 * 24)
__global__ __launch_bounds__(256)
void k_pre(const float* __restrict__ x, u16* __restrict__ xb,
           const float* __restrict__ w_qkv, u16* __restrict__ wqT,
           const float* __restrict__ w_out, u16* __restrict__ woT) {
  __shared__ float tile[32][33];
  const int bid = blockIdx.x;
  const int tid = threadIdx.x;
  if (bid < PRE_CAST_BLKS) {
    int i = bid * 256 + tid;
    f32x4 v = ((const f32x4*)x)[i];
    u16x4 o;
    o[0] = f2bf(v[0]); o[1] = f2bf(v[1]); o[2] = f2bf(v[2]); o[3] = f2bf(v[3]);
    ((u16x4*)xb)[i] = o;
    return;
  }
  const float* in;
  u16* out;
  int R, Cn, bx, by;
  if (bid < PRE_CAST_BLKS + PRE_TA_BLKS) {
    int q = bid - PRE_CAST_BLKS;
    bx = q % PRE_TA_BX; by = q / PRE_TA_BX;
    in = w_qkv; out = wqT; R = NC; Cn = 3 * NC;
  } else {
    int q = bid - PRE_CAST_BLKS - PRE_TA_BLKS;
    bx = q % PRE_TB_BX; by = q / PRE_TB_BX;
    in = w_out; out = woT; R = NC; Cn = NC;
  }
  int c0 = bx * 32, r0 = by * 32;
  int tx = tid & 31, ty = tid >> 5;
  for (int i = ty; i < 32; i += 8)
    tile[i][tx] = in[(size_t)(r0 + i) * Cn + c0 + tx];
  __syncthreads();
  for (int i = ty; i < 32; i += 8)
    out[(size_t)(c0 + i) * R + r0 + tx] = f2bf(tile[tx][i]);
}

// -------- GEMM: C[M,N] = A[M,K] * Bt[N,K]^T  (m97 structure, BK=64) --------
// THIS ROUND: supertile L2 walk.  Each XCD gets a contiguous nid range (T1);
// within it, blocks walk 8m x 3n SUPERTILES: working set = 8 A-panels
// (1.57MB) + 3 B-tiles (0.59MB) = 2.2MB < 4MB private L2, so A/B re-reads
// stay L2-resident.  Per-XCD L3 operand traffic drops ~3x (the r6-r10
// invariance showed gemms are refetch-bound, not core-bound).
// Staging via global_load_lds dwordx4 into LINEAR LDS with T21 pre-swizzled
// SOURCE granule ((lane&7)^lr); ds_read at granule (want ^ (lc&7)) is
// conflict-free.  EPI==1 V-section transposes through SMEM and stores V^T as
// coalesced 256B segments (proven r7).  MT = m-tiles (M/128), NBX%3==0.
template <int EPI, int NBX, int MT>
__global__ __launch_bounds__(256, 3)
void k_gemm_bt(const u16* __restrict__ A, const u16* __restrict__ Bt,
               int M, int N, int K,
               u16* __restrict__ o0, u16* __restrict__ o1, u16* __restrict__ o2,
               float* __restrict__ of) {
  __shared__ u16 SMEM[2 * 128 * 64];   // As | Bs (16KB each); epi reuse
  u16* As = SMEM;
  u16* Bs = SMEM + 8192;
  const int tid = threadIdx.x;
  const int wave = tid >> 6, lane = tid & 63, quad = lane >> 4, lc = lane & 15;
  const int wm = (wave & 1) * 64, wn = (wave >> 1) * 64;
  const int wg = blockIdx.x;
  const int nid = (wg & 7) * ((int)gridDim.x >> 3) + (wg >> 3);  // XCD-contig
  const int s = nid / 24, w = nid % 24;           // supertile of 24 blocks
  const int sm = s % (MT / 8), sn = s / (MT / 8);
  const int by = sm * 8 + (w & 7), bx = sn * 3 + (w >> 3);
  const int bm = by * 128, bn = bx * 128;

  // staging: wave wv, chunk c covers rows c*32 + wv*8 + lr (lr = lane>>3)
  const int lr = lane >> 3;
  const int gsw = ((lane & 7) ^ lr) * 8;          // pre-swizzled source granule
  const int rB = wave * 8 + lr;
  const u16* gA = A + (size_t)(bm + rB) * K + gsw;
  const u16* gB = Bt + (size_t)(bn + rB) * K + gsw;
  u16* lA0 = &As[wave * 8 * 64];                  // + c*2048 ; lane*16B linear
  u16* lB0 = &Bs[wave * 8 * 64];

  f32x4 zv = {0.f, 0.f, 0.f, 0.f};
  f32x4 acc[4][4];
#pragma unroll
  for (int i = 0; i < 4; ++i)
#pragma unroll
    for (int j = 0; j < 4; ++j) acc[i][j] = zv;

  for (int k0 = 0; k0 < K; k0 += 64) {
    __syncthreads();                 // prev iter's frag reads complete
#pragma unroll
    for (int c = 0; c < 4; ++c) {
      GLDS(gA + (size_t)c * 32 * K + k0, lA0 + c * 2048);
      GLDS(gB + (size_t)c * 32 * K + k0, lB0 + c * 2048);
    }
    asm volatile("s_waitcnt vmcnt(0)" ::: "memory");
    __syncthreads();                 // all waves' DMA landed

#pragma unroll
    for (int ks = 0; ks < 2; ++ks) {
      const int ao = (((ks << 2) + quad) ^ (lc & 7)) * 8;   // swizzled granule
      bf16x8 af[4], bfv[4];
#pragma unroll
      for (int mi = 0; mi < 4; ++mi)
        af[mi] = asbf(*(const u16x8*)&As[(wm + mi * 16 + lc) * 64 + ao]);
#pragma unroll
      for (int ni = 0; ni < 4; ++ni)
        bfv[ni] = asbf(*(const u16x8*)&Bs[(wn + ni * 16 + lc) * 64 + ao]);
#pragma unroll
      for (int mi = 0; mi < 4; ++mi)
#pragma unroll
        for (int ni = 0; ni < 4; ++ni)
          acc[mi][ni] = __builtin_amdgcn_mfma_f32_16x16x32_bf16(af[mi], bfv[ni],
                                                                acc[mi][ni], 0, 0, 0);
    }
  }

  const int sect = (EPI == 1) ? (bn / NC) : 0;   // block-uniform
  if (EPI == 1 && sect == 2) {
    // ---- V^T transposed epilogue through SMEM ----
    const int b = bm >> 12;
    const int tb = bm & (NT - 1);
    const int hb = (bn - 2 * NC) >> 6;
#pragma unroll 1
    for (int r2_ = 0; r2_ < 2; ++r2_) {
      __syncthreads();               // SMEM free / prev half read out
      if ((wave >> 1) == r2_) {      // waves owning wn == 64*r2_
#pragma unroll
        for (int mi = 0; mi < 4; ++mi)
#pragma unroll
          for (int ni = 0; ni < 4; ++ni) {
            const int nl = ni * 16 + lc;          // n within this 64-col half
#pragma unroll
            for (int r = 0; r < 4; ++r) {
              const int m = wm + mi * 16 + quad * 4 + r;
              SMEM[nl * 128 + (m ^ ((nl & 7) << 3))] = f2bf(acc[mi][ni][r]);
            }
          }
      }
      __syncthreads();
#pragma unroll
      for (int pass = 0; pass < 4; ++pass) {
        const int row = (tid >> 4) + 16 * pass;   // d-row within half
        const int chunk = tid & 15;               // 8-elem t-chunk
        u16x8 wv = *(const u16x8*)&SMEM[row * 128 + ((chunk ^ (row & 7)) * 8)];
        const int nl = 64 * r2_ + row;
        *(u16x8*)&o2[((size_t)(b * NH + hb + (nl >> 6)) * ND + (nl & 63)) * NT
                     + tb + chunk * 8] = wv;
      }
    }
    return;
  }

  const int mrow0 = bm + wm + quad * 4;
#pragma unroll
  for (int mi = 0; mi < 4; ++mi) {
    const int mbase = mrow0 + mi * 16;
#pragma unroll
    for (int ni = 0; ni < 4; ++ni) {
      const int n = bn + wn + ni * 16 + lc;
      if (EPI == 0) {
#pragma unroll
        for (int r = 0; r < 4; ++r)
          of[(size_t)(mbase + r) * N + n] = acc[mi][ni][r];
      } else {
        const int wn2 = n - sect * NC;
        const int h = wn2 >> 6, d = wn2 & 63;
        const int b = mbase >> 12;
        const int t = mbase & (NT - 1);
        const float sc = (sect == 0) ? 0.18033688011112042f : 1.0f;  // log2e/8
        u16* dst = (sect == 0) ? o0 : o1;
#pragma unroll
        for (int r = 0; r < 4; ++r)
          dst[((size_t)(b * NH + h) * NT + (t + r)) * ND + d] =
              f2bf(acc[mi][ni][r] * sc);
      }
    }
  }
}

// ============ flash attention (r8 structure) + ones-MFMA denominator ========
// Grid = 24 bh x 64 q-tiles (descending qi).  Block = 4 waves (qh, th); reg-
// staged K/V tile (16KB, XOR swizzle g^(row&7)); P in registers via pktr +
// permlane32_swap; raw v_exp_f32 (r8, -14 µs).
// THIS ROUND: the denominator comes from an all-ones A-fragment MFMA over the
// SAME truncated bf16 P operand the PV uses (lacc = mfma(ones, p, lacc) ->
// l[q] replicated in every acc row, lane q = l31).  Replaces 32 VALU/wave-tau
// of sl2 bit-twiddling + the epilogue shfl_xor with 2 MFMAs on the underused
// matrix pipe, and is exactly numerator-consistent by construction.
__device__ __forceinline__ void softpack16(const f32x16& s, int qrel, bool msk,
                                           int l5, bf16x8* pf) {
  float e[16];
#pragma unroll
  for (int r = 0; r < 16; ++r) {
    float v = s[r];
    if (msk) {
      int tl = (r & 3) + 8 * (r >> 2) + 4 * l5;   // 32x32 C-layout row
      v = (tl > qrel) ? -1e30f : v;
    }
    e[r] = __builtin_amdgcn_exp2f(v);
  }
  uint32_t wv[8];
#pragma unroll
  for (int i = 0; i < 8; ++i) wv[i] = pktr(e[2 * i], e[2 * i + 1]);
  // B-frag g covers t_local = g*16 + l5*8 + j; half-exchange = permlane32_swap
#pragma unroll
  for (int g = 0; g < 2; ++g) {
    auto r0 = __builtin_amdgcn_permlane32_swap(wv[g * 4 + 0], wv[g * 4 + 2], false, false);
    auto r1 = __builtin_amdgcn_permlane32_swap(wv[g * 4 + 1], wv[g * 4 + 3], false, false);
    u32x4 f = {r0[0], r1[0], r0[1], r1[1]};
    pf[g] = __builtin_bit_cast(bf16x8, f);
  }
}

__global__ __launch_bounds__(256, 3)
void k_attn(const u16* __restrict__ Q, const u16* __restrict__ K,
            const u16* __restrict__ Vt, u16* __restrict__ Y) {
  __shared__ u16 SM[2][64 * 64];   // [0]=K tile [t][d], [1]=V^T tile [d][t]
  __shared__ float PL[2][64];      // l park
  const int tid = threadIdx.x;
  const int lane = tid & 63, wave = tid >> 6;
  const int l5 = lane >> 5, l31 = lane & 31;
  const int qh = wave & 1, th = wave >> 1;
  const int bh = blockIdx.x % (NB * NH);
  const int qi = 63 - blockIdx.x / (NB * NH);      // long blocks first
  const int b = bh / NH, h = bh - b * NH;
  const u16* __restrict__ Qb = Q + (size_t)bh * NT * ND;
  const u16* __restrict__ Kb = K + (size_t)bh * NT * ND;
  const u16* __restrict__ Vb = Vt + (size_t)bh * (size_t)ND * NT;

  const int qg = qi * 64 + qh * 32 + l31;          // this lane's q column

  // Q as B-operand frags: col q = l31(+qh*32), k(d) = ks*16 + l5*8 + j
  bf16x8 bq[4];
#pragma unroll
  for (int ks = 0; ks < 4; ++ks)
    bq[ks] = asbf(*(const u16x8*)(Qb + (size_t)qg * ND + ks * 16 + l5 * 8));

  // all-ones A fragment (uniform -> layout-irrelevant) for the l-row MFMA
  u16x8 onesu;
#pragma unroll
  for (int i = 0; i < 8; ++i) onesu[i] = (u16)0x3F80;
  const bf16x8 ones = asbf(onesu);

  f32x16 Zv;
#pragma unroll
  for (int i = 0; i < 16; ++i) Zv[i] = 0.f;
  f32x16 o0 = Zv, o1 = Zv;     // O^T partial (d-halves), this wave's (qh,th)
  f32x16 lacc = Zv;            // denominator: every row = Sum_t P^T[t][l31]

  // staging: 256 thr x 4 x 16B = 16KB/iter; dest XOR-swizzled
  const int srow = tid >> 3, sg = tid & 7;
  const int soff = srow * 64 + ((sg ^ (srow & 7)) * 8);
  const u16* __restrict__ pK = Kb + (size_t)srow * ND + sg * 8;
  const u16* __restrict__ pV = Vb + (size_t)srow * NT + sg * 8;

  // LDS frag offsets (elements), matching XOR swizzle
  int qfro[4];
#pragma unroll
  for (int ks = 0; ks < 4; ++ks)
    qfro[ks] = (th * 32 + l31) * 64 + (((ks * 2 + l5) ^ (l31 & 7)) * 8);
  int vfro[2];
#pragma unroll
  for (int kp = 0; kp < 2; ++kp)
    vfro[kp] = l31 * 64 + ((((2 * th + kp) * 2 + l5) ^ (l31 & 7)) * 8);

  // prefetch tile 0
  u16x8 st[4];
  st[0] = *(const u16x8*)(pK);
  st[1] = *(const u16x8*)(pK + (size_t)32 * ND);
  st[2] = *(const u16x8*)(pV);
  st[3] = *(const u16x8*)(pV + (size_t)32 * NT);

#pragma unroll 1
  for (int tau = 0; tau <= qi; ++tau) {
    __syncthreads();
    *(u16x8*)&SM[0][soff] = st[0];
    *(u16x8*)&SM[0][2048 + soff] = st[1];
    *(u16x8*)&SM[1][soff] = st[2];
    *(u16x8*)&SM[1][2048 + soff] = st[3];
    __syncthreads();

    const bool dg = (tau == qi);
    const bool act = !(dg && th > qh);    // wave-uniform
    bf16x8 p[2];
    if (act) {
      // S^T[32t x 32q] = K(th half) Q(qh)^T ; first MFMA consumes Zv as C
      bf16x8 kf0 = asbf(*(const u16x8*)&SM[0][qfro[0]]);
      __builtin_amdgcn_s_setprio(1);
      f32x16 s = __builtin_amdgcn_mfma_f32_32x32x16_bf16(kf0, bq[0], Zv, 0, 0, 0);
#pragma unroll
      for (int ks = 1; ks < 4; ++ks) {
        bf16x8 kf = asbf(*(const u16x8*)&SM[0][qfro[ks]]);
        s = __builtin_amdgcn_mfma_f32_32x32x16_bf16(kf, bq[ks], s, 0, 0, 0);
      }
      __builtin_amdgcn_s_setprio(0);
      softpack16(s, l31, dg && (th == qh), l5, p);
    }

    // prefetch next tile (all threads; hides HBM latency under PV)
    if (tau < qi) {
      const int tn = (tau + 1) * 64;
      st[0] = *(const u16x8*)(pK + (size_t)tn * ND);
      st[1] = *(const u16x8*)(pK + (size_t)(tn + 32) * ND);
      st[2] = *(const u16x8*)(pV + tn);
      st[3] = *(const u16x8*)(pV + (size_t)32 * NT + tn);
    }

    if (act) {
      // O^T += V^T(d-halves) P^T ; l-row += ones P^T (same operand)
      __builtin_amdgcn_s_setprio(1);
#pragma unroll
      for (int kp = 0; kp < 2; ++kp) {
        bf16x8 v0 = asbf(*(const u16x8*)&SM[1][vfro[kp]]);
        bf16x8 v1 = asbf(*(const u16x8*)&SM[1][2048 + vfro[kp]]);
        o0 = __builtin_amdgcn_mfma_f32_32x32x16_bf16(v0, p[kp], o0, 0, 0, 0);
        o1 = __builtin_amdgcn_mfma_f32_32x32x16_bf16(v1, p[kp], o1, 0, 0, 0);
        lacc = __builtin_amdgcn_mfma_f32_32x32x16_bf16(ones, p[kp], lacc, 0, 0, 0);
      }
      __builtin_amdgcn_s_setprio(0);
    }
  }

  // ---- epilogue: l = lacc row 0 (all rows equal); th-pair via LDS park ----
  float l = lacc[0];
  __syncthreads();                       // done reading SM as K/V
  float* PK = (float*)&SM[0][0];         // 16KB park: [64 rows][64 lanes] f32
  if (th == 0) {
#pragma unroll
    for (int r = 0; r < 16; ++r) PK[(qh * 32 + r) * 64 + lane] = o0[r];
#pragma unroll
    for (int r = 0; r < 16; ++r) PK[(qh * 32 + 16 + r) * 64 + lane] = o1[r];
    PL[qh][lane] = l;
  }
  __syncthreads();
  if (th == 1) {
#pragma unroll
    for (int r = 0; r < 16; ++r) o0[r] += PK[(qh * 32 + r) * 64 + lane];
#pragma unroll
    for (int r = 0; r < 16; ++r) o1[r] += PK[(qh * 32 + 16 + r) * 64 + lane];
    l += PL[qh][lane];
    const float inv = 1.f / l;
    u16* yrow = Y + (size_t)(b * NT + qg) * NC + h * 64;
#pragma unroll
    for (int dh = 0; dh < 2; ++dh) {
      const f32x16& o = dh ? o1 : o0;
#pragma unroll
      for (int rq = 0; rq < 4; ++rq) {
        const int d = dh * 32 + 8 * rq + 4 * l5;
        uint2 w;
        w.x = pkbf(o[rq * 4 + 0] * inv, o[rq * 4 + 1] * inv);
        w.y = pkbf(o[rq * 4 + 2] * inv, o[rq * 4 + 3] * inv);
        *(uint2*)&yrow[d] = w;
      }
    }
  }
}

extern "C" void kernel_launch(void* const* d_in, const int* in_sizes, int n_in,
                              void* d_out, int out_size, void* d_ws, size_t ws_size,
                              hipStream_t stream) {
  (void)in_sizes; (void)n_in; (void)out_size; (void)ws_size;
  const float* x = (const float*)d_in[0];
  const float* w_qkv = (const float*)d_in[1];
  const float* w_out = (const float*)d_in[2];
  float* out = (float*)d_out;

  u16* ws = (u16*)d_ws;
  const size_t XE = (size_t)NB * NT * NC;       // 6291456 elements
  u16* xb  = ws;
  u16* wqT = xb + XE;
  u16* woT = wqT + (size_t)3 * NC * NC;
  u16* Qb  = woT + (size_t)NC * NC;
  u16* Kb  = Qb + XE;
  u16* Vtb = Kb + XE;
  u16* yb  = Vtb + XE;

  k_pre<<<dim3(PRE_CAST_BLKS + PRE_TA_BLKS + PRE_TB_BLKS), 256, 0, stream>>>(
      x, xb, w_qkv, wqT, w_out, woT);
  k_gemm_bt<1, 18, 64><<<dim3(18 * 64), 256, 0, stream>>>(
      xb, wqT, NB * NT, 3 * NC, NC, Qb, Kb, Vtb, nullptr);
  k_attn<<<dim3((NB * NH) * 64), 256, 0, stream>>>(Qb, Kb, Vtb, yb);
  k_gemm_bt<0, 6, 64><<<dim3(6 * 64), 256, 0, stream>>>(
      yb, woT, NB * NT, NC, NC, nullptr, nullptr, nullptr, out);
}

// Round 12
// 213.482 us; speedup vs baseline: 1.0399x; 1.0044x over previous
//
#include <hip/hip_runtime.h>
#include <stdint.h>
#include <stddef.h>

#define NB 2
#define NT 4096
#define NC 768
#define NH 12
#define ND 64

typedef unsigned short u16;
typedef __attribute__((ext_vector_type(4))) float f32x4;
typedef __attribute__((ext_vector_type(16))) float f32x16;
typedef __attribute__((ext_vector_type(8))) unsigned short u16x8;
typedef __attribute__((ext_vector_type(4))) unsigned short u16x4;
typedef __attribute__((ext_vector_type(8))) __bf16 bf16x8;
typedef __attribute__((ext_vector_type(4))) unsigned int u32x4;

typedef __attribute__((address_space(1))) const unsigned int gu32;
typedef __attribute__((address_space(3))) unsigned int lu32;

__device__ __forceinline__ u16 f2bf(float f) {
  uint32_t u = __builtin_bit_cast(uint32_t, f);
  u += 0x7FFFu + ((u >> 16) & 1u);   // RTNE
  return (u16)(u >> 16);
}
__device__ __forceinline__ bf16x8 asbf(u16x8 v) { return __builtin_bit_cast(bf16x8, v); }

// pack two f32 -> two bf16, round-half-up: 3 VALU
__device__ __forceinline__ uint32_t pkbf(float a, float b) {
  uint32_t ua = __builtin_bit_cast(uint32_t, a) + 0x8000u;
  uint32_t ub = __builtin_bit_cast(uint32_t, b) + 0x8000u;
  return __builtin_amdgcn_perm(ub, ua, 0x07060302u);
}
// truncating pack (P only; numerator/denominator stay consistent): 1 VALU
__device__ __forceinline__ uint32_t pktr(float a, float b) {
  return __builtin_amdgcn_perm(__builtin_bit_cast(uint32_t, b),
                               __builtin_bit_cast(uint32_t, a), 0x07060302u);
}

#define GLDS(gsrc, ldst) __builtin_amdgcn_global_load_lds( \
    (gu32*)(gsrc), (lu32*)(ldst), 16, 0, 0)

// ------- merged preprocessing: cast(x) + transpose(w_qkv) + transpose(w_out)
#define PRE_CAST_BLKS 6144             // (NB*NT*NC/4)/256
#define PRE_TA_BX 72                   // 3*NC/32
#define PRE_TA_BLKS (72 * 24)
#define PRE_TB_BX 24                   // NC/32
#define PRE_TB_BLKS (24 * 24)
__global__ __launch_bounds__(256)
void k_pre(const float* __restrict__ x, u16* __restrict__ xb,
           const float* __restrict__ w_qkv, u16* __restrict__ wqT,
           const float* __restrict__ w_out, u16* __restrict__ woT) {
  __shared__ float tile[32][33];
  const int bid = blockIdx.x;
  const int tid = threadIdx.x;
  if (bid < PRE_CAST_BLKS) {
    int i = bid * 256 + tid;
    f32x4 v = ((const f32x4*)x)[i];
    u16x4 o;
    o[0] = f2bf(v[0]); o[1] = f2bf(v[1]); o[2] = f2bf(v[2]); o[3] = f2bf(v[3]);
    ((u16x4*)xb)[i] = o;
    return;
  }
  const float* in;
  u16* out;
  int R, Cn, bx, by;
  if (bid < PRE_CAST_BLKS + PRE_TA_BLKS) {
    int q = bid - PRE_CAST_BLKS;
    bx = q % PRE_TA_BX; by = q / PRE_TA_BX;
    in = w_qkv; out = wqT; R = NC; Cn = 3 * NC;
  } else {
    int q = bid - PRE_CAST_BLKS - PRE_TA_BLKS;
    bx = q % PRE_TB_BX; by = q / PRE_TB_BX;
    in = w_out; out = woT; R = NC; Cn = NC;
  }
  int c0 = bx * 32, r0 = by * 32;
  int tx = tid & 31, ty = tid >> 5;
  for (int i = ty; i < 32; i += 8)
    tile[i][tx] = in[(size_t)(r0 + i) * Cn + c0 + tx];
  __syncthreads();
  for (int i = ty; i < 32; i += 8)
    out[(size_t)(c0 + i) * R + r0 + tx] = f2bf(tile[tx][i]);
}

// ---- GEMM: C[M,N] = A[M,K] * Bt[N,K]^T  (2-phase counted-vmcnt dbuf) ----
// THIS ROUND (T3/T4 minimum 2-phase): double-buffered LDS (2 x 32KB) with
// counted s_waitcnt vmcnt(8) + raw barriers.  Loop: issue tile t+1's 8 DMAs
// into buf^1, wait vmcnt(8) (= tile t's 8 landed, t+1's stay IN FLIGHT
// across both barriers and the MFMA cluster), barrier, compute, barrier.
// Removes the full ~300-500cyc drain the 1-phase loop paid every K-step
// (compute is only ~160cyc -> the drain dominated; r6-r11 core rewrites all
// nulled because the schedule, not the core, was the limit).
// Supertile L2 walk (r11) + T21 pre-swizzled GLDS source + conflict-free
// swizzled ds_reads (r8) carried over.  EPI==1 V-section transposes through
// SMEM buf0 and stores V^T as coalesced 256B segments (r7).
template <int EPI, int NBX, int MT>
__global__ __launch_bounds__(256, 2)
void k_gemm_bt(const u16* __restrict__ A, const u16* __restrict__ Bt,
               int M, int N, int K,
               u16* __restrict__ o0, u16* __restrict__ o1, u16* __restrict__ o2,
               float* __restrict__ of) {
  __shared__ u16 SMEM[2 * 16384];      // buf p: As = +p*16384, Bs = +8192
  const int tid = threadIdx.x;
  const int wave = tid >> 6, lane = tid & 63, quad = lane >> 4, lc = lane & 15;
  const int wm = (wave & 1) * 64, wn = (wave >> 1) * 64;
  const int wg = blockIdx.x;
  const int nid = (wg & 7) * ((int)gridDim.x >> 3) + (wg >> 3);  // XCD-contig
  const int s = nid / 24, w = nid % 24;           // supertile of 24 blocks
  const int sm = s % (MT / 8), sn = s / (MT / 8);
  const int by = sm * 8 + (w & 7), bx = sn * 3 + (w >> 3);
  const int bm = by * 128, bn = bx * 128;

  // staging: wave wv, chunk c covers rows c*32 + wv*8 + lr (lr = lane>>3)
  const int lr = lane >> 3;
  const int gsw = ((lane & 7) ^ lr) * 8;          // pre-swizzled source granule
  const int rB = wave * 8 + lr;
  const u16* gA = A + (size_t)(bm + rB) * K + gsw;
  const u16* gB = Bt + (size_t)(bn + rB) * K + gsw;

  f32x4 zv = {0.f, 0.f, 0.f, 0.f};
  f32x4 acc[4][4];
#pragma unroll
  for (int i = 0; i < 4; ++i)
#pragma unroll
    for (int j = 0; j < 4; ++j) acc[i][j] = zv;

  const int nt = K >> 6;               // 64-wide K-steps
  // prologue: tile 0 -> buf 0 (8 DMAs/wave in flight)
  {
    u16* dA = SMEM + wave * 512;
    u16* dB = SMEM + 8192 + wave * 512;
#pragma unroll
    for (int c = 0; c < 4; ++c) {
      GLDS(gA + (size_t)c * 32 * K, dA + c * 2048);
      GLDS(gB + (size_t)c * 32 * K, dB + c * 2048);
    }
  }

#pragma unroll 1
  for (int t = 0; t < nt; ++t) {
    const int p = t & 1;
    if (t + 1 < nt) {                  // issue next tile into other buffer
      const int k0 = (t + 1) * 64;
      u16* dA = SMEM + (p ^ 1) * 16384 + wave * 512;
      u16* dB = SMEM + (p ^ 1) * 16384 + 8192 + wave * 512;
#pragma unroll
      for (int c = 0; c < 4; ++c) {
        GLDS(gA + (size_t)c * 32 * K + k0, dA + c * 2048);
        GLDS(gB + (size_t)c * 32 * K + k0, dB + c * 2048);
      }
      asm volatile("s_waitcnt vmcnt(8)" ::: "memory");  // tile t landed
    } else {
      asm volatile("s_waitcnt vmcnt(0)" ::: "memory");
    }
    __builtin_amdgcn_s_barrier();      // all waves' tile-t DMA complete

    const u16* As = SMEM + p * 16384;
    const u16* Bs = As + 8192;
#pragma unroll
    for (int ks = 0; ks < 2; ++ks) {
      const int ao = (((ks << 2) + quad) ^ (lc & 7)) * 8;   // swizzled granule
      bf16x8 af[4], bfv[4];
#pragma unroll
      for (int mi = 0; mi < 4; ++mi)
        af[mi] = asbf(*(const u16x8*)&As[(wm + mi * 16 + lc) * 64 + ao]);
#pragma unroll
      for (int ni = 0; ni < 4; ++ni)
        bfv[ni] = asbf(*(const u16x8*)&Bs[(wn + ni * 16 + lc) * 64 + ao]);
      __builtin_amdgcn_s_setprio(1);
#pragma unroll
      for (int mi = 0; mi < 4; ++mi)
#pragma unroll
        for (int ni = 0; ni < 4; ++ni)
          acc[mi][ni] = __builtin_amdgcn_mfma_f32_16x16x32_bf16(af[mi], bfv[ni],
                                                                acc[mi][ni], 0, 0, 0);
      __builtin_amdgcn_s_setprio(0);
    }
    __builtin_amdgcn_s_barrier();      // all waves done reading buf p
  }

  const int sect = (EPI == 1) ? (bn / NC) : 0;   // block-uniform
  if (EPI == 1 && sect == 2) {
    // ---- V^T transposed epilogue through SMEM (buf 0 region) ----
    const int b = bm >> 12;
    const int tb = bm & (NT - 1);
    const int hb = (bn - 2 * NC) >> 6;
#pragma unroll 1
    for (int r2_ = 0; r2_ < 2; ++r2_) {
      __syncthreads();               // SMEM free / prev half read out
      if ((wave >> 1) == r2_) {      // waves owning wn == 64*r2_
#pragma unroll
        for (int mi = 0; mi < 4; ++mi)
#pragma unroll
          for (int ni = 0; ni < 4; ++ni) {
            const int nl = ni * 16 + lc;          // n within this 64-col half
#pragma unroll
            for (int r = 0; r < 4; ++r) {
              const int m = wm + mi * 16 + quad * 4 + r;
              SMEM[nl * 128 + (m ^ ((nl & 7) << 3))] = f2bf(acc[mi][ni][r]);
            }
          }
      }
      __syncthreads();
#pragma unroll
      for (int pass = 0; pass < 4; ++pass) {
        const int row = (tid >> 4) + 16 * pass;   // d-row within half
        const int chunk = tid & 15;               // 8-elem t-chunk
        u16x8 wv = *(const u16x8*)&SMEM[row * 128 + ((chunk ^ (row & 7)) * 8)];
        const int nl = 64 * r2_ + row;
        *(u16x8*)&o2[((size_t)(b * NH + hb + (nl >> 6)) * ND + (nl & 63)) * NT
                     + tb + chunk * 8] = wv;
      }
    }
    return;
  }

  const int mrow0 = bm + wm + quad * 4;
#pragma unroll
  for (int mi = 0; mi < 4; ++mi) {
    const int mbase = mrow0 + mi * 16;
#pragma unroll
    for (int ni = 0; ni < 4; ++ni) {
      const int n = bn + wn + ni * 16 + lc;
      if (EPI == 0) {
#pragma unroll
        for (int r = 0; r < 4; ++r)
          of[(size_t)(mbase + r) * N + n] = acc[mi][ni][r];
      } else {
        const int wn2 = n - sect * NC;
        const int h = wn2 >> 6, d = wn2 & 63;
        const int b = mbase >> 12;
        const int t = mbase & (NT - 1);
        const float sc = (sect == 0) ? 0.18033688011112042f : 1.0f;  // log2e/8
        u16* dst = (sect == 0) ? o0 : o1;
#pragma unroll
        for (int r = 0; r < 4; ++r)
          dst[((size_t)(b * NH + h) * NT + (t + r)) * ND + d] =
              f2bf(acc[mi][ni][r] * sc);
      }
    }
  }
}

// ============ flash attention (r11, frozen): ones-MFMA denominator ==========
// Grid = 24 bh x 64 q-tiles (descending qi).  Block = 4 waves (qh, th); reg-
// staged K/V tile (16KB, XOR swizzle g^(row&7)); P in registers via pktr +
// permlane32_swap; raw v_exp_f32 (r8); denominator via all-ones A-fragment
// MFMA over the same truncated P operand (r11: VALU 47->43, Mfma 26->36).
__device__ __forceinline__ void softpack16(const f32x16& s, int qrel, bool msk,
                                           int l5, bf16x8* pf) {
  float e[16];
#pragma unroll
  for (int r = 0; r < 16; ++r) {
    float v = s[r];
    if (msk) {
      int tl = (r & 3) + 8 * (r >> 2) + 4 * l5;   // 32x32 C-layout row
      v = (tl > qrel) ? -1e30f : v;
    }
    e[r] = __builtin_amdgcn_exp2f(v);
  }
  uint32_t wv[8];
#pragma unroll
  for (int i = 0; i < 8; ++i) wv[i] = pktr(e[2 * i], e[2 * i + 1]);
  // B-frag g covers t_local = g*16 + l5*8 + j; half-exchange = permlane32_swap
#pragma unroll
  for (int g = 0; g < 2; ++g) {
    auto r0 = __builtin_amdgcn_permlane32_swap(wv[g * 4 + 0], wv[g * 4 + 2], false, false);
    auto r1 = __builtin_amdgcn_permlane32_swap(wv[g * 4 + 1], wv[g * 4 + 3], false, false);
    u32x4 f = {r0[0], r1[0], r0[1], r1[1]};
    pf[g] = __builtin_bit_cast(bf16x8, f);
  }
}

__global__ __launch_bounds__(256, 3)
void k_attn(const u16* __restrict__ Q, const u16* __restrict__ K,
            const u16* __restrict__ Vt, u16* __restrict__ Y) {
  __shared__ u16 SM[2][64 * 64];   // [0]=K tile [t][d], [1]=V^T tile [d][t]
  __shared__ float PL[2][64];      // l park
  const int tid = threadIdx.x;
  const int lane = tid & 63, wave = tid >> 6;
  const int l5 = lane >> 5, l31 = lane & 31;
  const int qh = wave & 1, th = wave >> 1;
  const int bh = blockIdx.x % (NB * NH);
  const int qi = 63 - blockIdx.x / (NB * NH);      // long blocks first
  const int b = bh / NH, h = bh - b * NH;
  const u16* __restrict__ Qb = Q + (size_t)bh * NT * ND;
  const u16* __restrict__ Kb = K + (size_t)bh * NT * ND;
  const u16* __restrict__ Vb = Vt + (size_t)bh * (size_t)ND * NT;

  const int qg = qi * 64 + qh * 32 + l31;          // this lane's q column

  // Q as B-operand frags: col q = l31(+qh*32), k(d) = ks*16 + l5*8 + j
  bf16x8 bq[4];
#pragma unroll
  for (int ks = 0; ks < 4; ++ks)
    bq[ks] = asbf(*(const u16x8*)(Qb + (size_t)qg * ND + ks * 16 + l5 * 8));

  // all-ones A fragment (uniform -> layout-irrelevant) for the l-row MFMA
  u16x8 onesu;
#pragma unroll
  for (int i = 0; i < 8; ++i) onesu[i] = (u16)0x3F80;
  const bf16x8 ones = asbf(onesu);

  f32x16 Zv;
#pragma unroll
  for (int i = 0; i < 16; ++i) Zv[i] = 0.f;
  f32x16 o0 = Zv, o1 = Zv;     // O^T partial (d-halves), this wave's (qh,th)
  f32x16 lacc = Zv;            // denominator: every row = Sum_t P^T[t][l31]

  // staging: 256 thr x 4 x 16B = 16KB/iter; dest XOR-swizzled
  const int srow = tid >> 3, sg = tid & 7;
  const int soff = srow * 64 + ((sg ^ (srow & 7)) * 8);
  const u16* __restrict__ pK = Kb + (size_t)srow * ND + sg * 8;
  const u16* __restrict__ pV = Vb + (size_t)srow * NT + sg * 8;

  // LDS frag offsets (elements), matching XOR swizzle
  int qfro[4];
#pragma unroll
  for (int ks = 0; ks < 4; ++ks)
    qfro[ks] = (th * 32 + l31) * 64 + (((ks * 2 + l5) ^ (l31 & 7)) * 8);
  int vfro[2];
#pragma unroll
  for (int kp = 0; kp < 2; ++kp)
    vfro[kp] = l31 * 64 + ((((2 * th + kp) * 2 + l5) ^ (l31 & 7)) * 8);

  // prefetch tile 0
  u16x8 st[4];
  st[0] = *(const u16x8*)(pK);
  st[1] = *(const u16x8*)(pK + (size_t)32 * ND);
  st[2] = *(const u16x8*)(pV);
  st[3] = *(const u16x8*)(pV + (size_t)32 * NT);

#pragma unroll 1
  for (int tau = 0; tau <= qi; ++tau) {
    __syncthreads();
    *(u16x8*)&SM[0][soff] = st[0];
    *(u16x8*)&SM[0][2048 + soff] = st[1];
    *(u16x8*)&SM[1][soff] = st[2];
    *(u16x8*)&SM[1][2048 + soff] = st[3];
    __syncthreads();

    const bool dg = (tau == qi);
    const bool act = !(dg && th > qh);    // wave-uniform
    bf16x8 p[2];
    if (act) {
      // S^T[32t x 32q] = K(th half) Q(qh)^T ; first MFMA consumes Zv as C
      bf16x8 kf0 = asbf(*(const u16x8*)&SM[0][qfro[0]]);
      __builtin_amdgcn_s_setprio(1);
      f32x16 s = __builtin_amdgcn_mfma_f32_32x32x16_bf16(kf0, bq[0], Zv, 0, 0, 0);
#pragma unroll
      for (int ks = 1; ks < 4; ++ks) {
        bf16x8 kf = asbf(*(const u16x8*)&SM[0][qfro[ks]]);
        s = __builtin_amdgcn_mfma_f32_32x32x16_bf16(kf, bq[ks], s, 0, 0, 0);
      }
      __builtin_amdgcn_s_setprio(0);
      softpack16(s, l31, dg && (th == qh), l5, p);
    }

    // prefetch next tile (all threads; hides HBM latency under PV)
    if (tau < qi) {
      const int tn = (tau + 1) * 64;
      st[0] = *(const u16x8*)(pK + (size_t)tn * ND);
      st[1] = *(const u16x8*)(pK + (size_t)(tn + 32) * ND);
      st[2] = *(const u16x8*)(pV + tn);
      st[3] = *(const u16x8*)(pV + (size_t)32 * NT + tn);
    }

    if (act) {
      // O^T += V^T(d-halves) P^T ; l-row += ones P^T (same operand)
      __builtin_amdgcn_s_setprio(1);
#pragma unroll
      for (int kp = 0; kp < 2; ++kp) {
        bf16x8 v0 = asbf(*(const u16x8*)&SM[1][vfro[kp]]);
        bf16x8 v1 = asbf(*(const u16x8*)&SM[1][2048 + vfro[kp]]);
        o0 = __builtin_amdgcn_mfma_f32_32x32x16_bf16(v0, p[kp], o0, 0, 0, 0);
        o1 = __builtin_amdgcn_mfma_f32_32x32x16_bf16(v1, p[kp], o1, 0, 0, 0);
        lacc = __builtin_amdgcn_mfma_f32_32x32x16_bf16(ones, p[kp], lacc, 0, 0, 0);
      }
      __builtin_amdgcn_s_setprio(0);
    }
  }

  // ---- epilogue: l = lacc row 0 (all rows equal); th-pair via LDS park ----
  float l = lacc[0];
  __syncthreads();                       // done reading SM as K/V
  float* PK = (float*)&SM[0][0];         // 16KB park: [64 rows][64 lanes] f32
  if (th == 0) {
#pragma unroll
    for (int r = 0; r < 16; ++r) PK[(qh * 32 + r) * 64 + lane] = o0[r];
#pragma unroll
    for (int r = 0; r < 16; ++r) PK[(qh * 32 + 16 + r) * 64 + lane] = o1[r];
    PL[qh][lane] = l;
  }
  __syncthreads();
  if (th == 1) {
#pragma unroll
    for (int r = 0; r < 16; ++r) o0[r] += PK[(qh * 32 + r) * 64 + lane];
#pragma unroll
    for (int r = 0; r < 16; ++r) o1[r] += PK[(qh * 32 + 16 + r) * 64 + lane];
    l += PL[qh][lane];
    const float inv = 1.f / l;
    u16* yrow = Y + (size_t)(b * NT + qg) * NC + h * 64;
#pragma unroll
    for (int dh = 0; dh < 2; ++dh) {
      const f32x16& o = dh ? o1 : o0;
#pragma unroll
      for (int rq = 0; rq < 4; ++rq) {
        const int d = dh * 32 + 8 * rq + 4 * l5;
        uint2 w;
        w.x = pkbf(o[rq * 4 + 0] * inv, o[rq * 4 + 1] * inv);
        w.y = pkbf(o[rq * 4 + 2] * inv, o[rq * 4 + 3] * inv);
        *(uint2*)&yrow[d] = w;
      }
    }
  }
}

extern "C" void kernel_launch(void* const* d_in, const int* in_sizes, int n_in,
                              void* d_out, int out_size, void* d_ws, size_t ws_size,
                              hipStream_t stream) {
  (void)in_sizes; (void)n_in; (void)out_size; (void)ws_size;
  const float* x = (const float*)d_in[0];
  const float* w_qkv = (const float*)d_in[1];
  const float* w_out = (const float*)d_in[2];
  float* out = (float*)d_out;

  u16* ws = (u16*)d_ws;
  const size_t XE = (size_t)NB * NT * NC;       // 6291456 elements
  u16* xb  = ws;
  u16* wqT = xb + XE;
  u16* woT = wqT + (size_t)3 * NC * NC;
  u16* Qb  = woT + (size_t)NC * NC;
  u16* Kb  = Qb + XE;
  u16* Vtb = Kb + XE;
  u16* yb  = Vtb + XE;

  k_pre<<<dim3(PRE_CAST_BLKS + PRE_TA_BLKS + PRE_TB_BLKS), 256, 0, stream>>>(
      x, xb, w_qkv, wqT, w_out, woT);
  k_gemm_bt<1, 18, 64><<<dim3(18 * 64), 256, 0, stream>>>(
      xb, wqT, NB * NT, 3 * NC, NC, Qb, Kb, Vtb, nullptr);
  k_attn<<<dim3((NB * NH) * 64), 256, 0, stream>>>(Qb, Kb, Vtb, yb);
  k_gemm_bt<0, 6, 64><<<dim3(6 * 64), 256, 0, stream>>>(
      yb, woT, NB * NT, NC, NC, nullptr, nullptr, nullptr, out);
}